// Round 8
// baseline (320.105 us; speedup 1.0000x reference)
//
#include <hip/hip_runtime.h>

// B=4, C=256, C8=32, N=4096. fp16 MFMA: 16x16x32 (S, proj), 32x32x16 (PV).
#define BB 4
#define CC 256
#define NN 4096

typedef _Float16 half_t;
typedef __attribute__((ext_vector_type(8))) _Float16 half8;
typedef __attribute__((ext_vector_type(4))) _Float16 half4;
typedef __attribute__((ext_vector_type(4))) float floatx4;
typedef __attribute__((ext_vector_type(16))) float floatx16;

// ---------------------------------------------------------------------------
// cvt_w: cast the six weight matrices to fp16. grid (64, 6).
// ---------------------------------------------------------------------------
__global__ __launch_bounds__(256)
void cvt_w_kernel(const float* __restrict__ Wfx, const float* __restrict__ Wgx,
                  const float* __restrict__ Whx, const float* __restrict__ Wfy,
                  const float* __restrict__ Wgy, const float* __restrict__ Why,
                  half_t* __restrict__ oWfx, half_t* __restrict__ oWgx,
                  half_t* __restrict__ oWhx, half_t* __restrict__ oWfy,
                  half_t* __restrict__ oWgy, half_t* __restrict__ oWhy)
{
    const float* src; half_t* dst; int n;
    switch (blockIdx.y) {
        case 0: src = Wfx; dst = oWfx; n = 32 * CC; break;
        case 1: src = Wgx; dst = oWgx; n = 32 * CC; break;
        case 2: src = Whx; dst = oWhx; n = CC * CC; break;
        case 3: src = Wfy; dst = oWfy; n = 32 * CC; break;
        case 4: src = Wgy; dst = oWgy; n = 32 * CC; break;
        default: src = Why; dst = oWhy; n = CC * CC; break;
    }
    int idx = (blockIdx.x * 256 + threadIdx.x) * 4;
    if (idx >= n) return;
    float4 v = *(const float4*)&src[idx];
    half4 h; h[0] = (half_t)v.x; h[1] = (half_t)v.y; h[2] = (half_t)v.z; h[3] = (half_t)v.w;
    *(half4*)&dst[idx] = h;
}

// ---------------------------------------------------------------------------
// transpose_cvt: xT[b][n][c] fp16 from in[b][c][n] fp32. grid (64, 4, 8).
// ---------------------------------------------------------------------------
__global__ __launch_bounds__(256)
void transpose_cvt_kernel(const float* __restrict__ x, const float* __restrict__ y,
                          half_t* __restrict__ xTx, half_t* __restrict__ xTy)
{
    const int n0 = blockIdx.x * 64;
    const int c0 = blockIdx.y * 64;
    const int b  = blockIdx.z & 3;
    const int sel = blockIdx.z >> 2;
    const float* in = sel ? y : x;
    half_t* outT = sel ? xTy : xTx;
    const int t  = threadIdx.x;
    const int ch = t & 7, nl = t >> 3;            // 8 c-chunks x 32 n
    const float* inb = in + (size_t)b * CC * NN;
    half_t* outb = outT + (size_t)b * NN * CC;

    #pragma unroll
    for (int p = 0; p < 2; ++p) {
        int n = n0 + nl + 32 * p;
        half8 hv;
        #pragma unroll
        for (int j = 0; j < 8; ++j)
            hv[j] = (half_t)inb[(size_t)(c0 + 8 * ch + j) * NN + n];
        *(half8*)&outb[(size_t)n * CC + c0 + 8 * ch] = hv;
    }
}

// ---------------------------------------------------------------------------
// proj_fg (MFMA): fT[n][32], gT[n][32]. grid (64, 4, 2): z = sel.
// ---------------------------------------------------------------------------
__global__ __launch_bounds__(256)
void proj_fg_kernel(const half_t* __restrict__ xTx, const half_t* __restrict__ xTy,
                    const half_t* __restrict__ Wfx, const half_t* __restrict__ Wgx,
                    const half_t* __restrict__ Wfy, const half_t* __restrict__ Wgy,
                    const float* __restrict__ bfx, const float* __restrict__ bgx,
                    const float* __restrict__ bfy, const float* __restrict__ bgy,
                    half_t* __restrict__ fxT, half_t* __restrict__ gxT,
                    half_t* __restrict__ fyT, half_t* __restrict__ gyT)
{
    const int n0 = blockIdx.x * 64;
    const int b  = blockIdx.y;
    const int sel = blockIdx.z;
    const half_t* xT = sel ? xTy : xTx;
    const half_t* Wf = sel ? Wfy : Wfx;
    const half_t* Wg = sel ? Wgy : Wgx;
    const float*  bf = sel ? bfy : bfx;
    const float*  bg = sel ? bgy : bgx;
    half_t* fT = sel ? fyT : fxT;
    half_t* gT = sel ? gyT : gxT;

    const int t  = threadIdx.x;
    const int w = t >> 6, lane = t & 63, q = lane >> 4, mc = lane & 15;
    const half_t* xTb = xT + (size_t)b * NN * CC;

    floatx4 acc[4];
    #pragma unroll
    for (int i = 0; i < 4; ++i) {
        float bv = (i < 2 ? bf : bg)[(i & 1) * 16 + mc];
        acc[i] = (floatx4){bv, bv, bv, bv};
    }

    #pragma unroll
    for (int ks = 0; ks < 8; ++ks) {
        int k0 = ks * 32 + q * 8;
        half8 af = *(const half8*)&xTb[(size_t)(n0 + w * 16 + mc) * CC + k0];
        #pragma unroll
        for (int i = 0; i < 4; ++i) {
            const half_t* Ws = (i < 2) ? Wf : Wg;
            half8 bfr = *(const half8*)&Ws[(size_t)((i & 1) * 16 + mc) * CC + k0];
            acc[i] = __builtin_amdgcn_mfma_f32_16x16x32_f16(af, bfr, acc[i], 0, 0, 0);
        }
    }

    #pragma unroll
    for (int i = 0; i < 4; ++i) {
        half_t* dst = (i < 2) ? fT : gT;
        #pragma unroll
        for (int r = 0; r < 4; ++r) {
            int n = n0 + w * 16 + q * 4 + r;
            dst[((size_t)b * NN + n) * 32 + (i & 1) * 16 + mc] = (half_t)acc[i][r];
        }
    }
}

// ---------------------------------------------------------------------------
// proj_h (MFMA): h[o][n] plain layout (R4-verified). grid (64, 2, 8).
// ---------------------------------------------------------------------------
__global__ __launch_bounds__(256)
void proj_h_kernel(const half_t* __restrict__ xTx, const half_t* __restrict__ xTy,
                   const half_t* __restrict__ Whx, const half_t* __restrict__ Why,
                   const float* __restrict__ bhx, const float* __restrict__ bhy,
                   half_t* __restrict__ hx, half_t* __restrict__ hy)
{
    const int n0 = blockIdx.x * 64;
    const int o0 = blockIdx.y * 128;
    const int b  = blockIdx.z & 3;
    const int sel = blockIdx.z >> 2;
    const half_t* xT = sel ? xTy : xTx;
    const half_t* Wh = sel ? Why : Whx;
    const float*  bh = sel ? bhy : bhx;
    half_t* h = sel ? hy : hx;

    const int t  = threadIdx.x;
    const int w = t >> 6, lane = t & 63, q = lane >> 4, mc = lane & 15;
    const half_t* xTb = xT + (size_t)b * NN * CC;
    half_t* hb = h + (size_t)b * CC * NN;

    floatx4 acc[2][4];
    #pragma unroll
    for (int j = 0; j < 2; ++j) {
        floatx4 bv;
        #pragma unroll
        for (int r = 0; r < 4; ++r) bv[r] = bh[o0 + w * 32 + j * 16 + q * 4 + r];
        #pragma unroll
        for (int i = 0; i < 4; ++i) acc[j][i] = bv;
    }

    #pragma unroll
    for (int ks = 0; ks < 8; ++ks) {
        int k0 = ks * 32 + q * 8;
        half8 a0 = *(const half8*)&Wh[(size_t)(o0 + w * 32 + mc) * CC + k0];
        half8 a1 = *(const half8*)&Wh[(size_t)(o0 + w * 32 + 16 + mc) * CC + k0];
        #pragma unroll
        for (int i = 0; i < 4; ++i) {
            half8 bfr = *(const half8*)&xTb[(size_t)(n0 + i * 16 + mc) * CC + k0];
            acc[0][i] = __builtin_amdgcn_mfma_f32_16x16x32_f16(a0, bfr, acc[0][i], 0, 0, 0);
            acc[1][i] = __builtin_amdgcn_mfma_f32_16x16x32_f16(a1, bfr, acc[1][i], 0, 0, 0);
        }
    }

    #pragma unroll
    for (int j = 0; j < 2; ++j)
        #pragma unroll
        for (int i = 0; i < 4; ++i)
            #pragma unroll
            for (int r = 0; r < 4; ++r) {
                int o = o0 + w * 32 + j * 16 + q * 4 + r;
                hb[(size_t)o * NN + n0 + i * 16 + mc] = (half_t)acc[j][i][r];
            }
}

// ---------------------------------------------------------------------------
// stats: Llog2[n] = -log2( sum_m exp(S[n,m]) ). grid (128, 4, 2).
// ---------------------------------------------------------------------------
__global__ __launch_bounds__(256)
void stats_kernel(const half_t* __restrict__ fT0, const half_t* __restrict__ gT0,
                  const half_t* __restrict__ fT1, const half_t* __restrict__ gT1,
                  float* __restrict__ L0, float* __restrict__ L1)
{
    __shared__ float red_l[4][32];
    const int b  = blockIdx.y;
    const int sel = blockIdx.z;
    const half_t* fT = sel ? fT1 : fT0;
    const half_t* gT = sel ? gT1 : gT0;
    float* Lout = sel ? L1 : L0;

    const int n0 = blockIdx.x * 32;
    const int t  = threadIdx.x;
    const int w = t >> 6, lane = t & 63, q = lane >> 4, mc = lane & 15;
    const half_t* fTb = fT + (size_t)b * NN * 32;
    const half_t* gTb = gT + (size_t)b * NN * 32;

    half8 a0 = *(const half8*)&fTb[(size_t)(n0 + mc) * 32 + q * 8];
    half8 a1 = *(const half8*)&fTb[(size_t)(n0 + 16 + mc) * 32 + q * 8];

    float l0[4] = {0.f, 0.f, 0.f, 0.f}, l1[4] = {0.f, 0.f, 0.f, 0.f};
    for (int it = 0; it < NN / 64; ++it) {
        int m = (it * 4 + w) * 16 + mc;
        half8 bfr = *(const half8*)&gTb[(size_t)m * 32 + q * 8];
        floatx4 S0 = __builtin_amdgcn_mfma_f32_16x16x32_f16(a0, bfr, (floatx4){0.f,0.f,0.f,0.f}, 0, 0, 0);
        floatx4 S1 = __builtin_amdgcn_mfma_f32_16x16x32_f16(a1, bfr, (floatx4){0.f,0.f,0.f,0.f}, 0, 0, 0);
        #pragma unroll
        for (int r = 0; r < 4; ++r) { l0[r] += __expf(S0[r]); l1[r] += __expf(S1[r]); }
    }
    #pragma unroll
    for (int r = 0; r < 4; ++r) {
        #pragma unroll
        for (int off = 1; off < 16; off <<= 1) {
            l0[r] += __shfl_xor(l0[r], off);
            l1[r] += __shfl_xor(l1[r], off);
        }
    }
    if (mc == 0)
        #pragma unroll
        for (int r = 0; r < 4; ++r) {
            red_l[w][q * 4 + r]      = l0[r];
            red_l[w][16 + q * 4 + r] = l1[r];
        }
    __syncthreads();
    if (t < 32) {
        float L = red_l[0][t] + red_l[1][t] + red_l[2][t] + red_l[3][t];
        Lout[(size_t)b * NN + n0 + t] = -log2f(L);
    }
}

// ---------------------------------------------------------------------------
// pv: out[c,m] = src[c,m] + gamma * sum_n h[c,n] * exp2(S*log2e + Llog2[n]).
// R7 structure + single-barrier ping-pong: double-buffered h_lds/PT; iter i
// stages tile i into buf (i&1), PV consumes tile i-1 from buf ((i-1)&1).
// One __syncthreads per tile (write-after-read ordered by next barrier).
// grid (32, 2, 8), block tile 128c x 128m; wave = 64c x 64m.
// ---------------------------------------------------------------------------
__global__ __launch_bounds__(256)
void pv_kernel(const half_t* __restrict__ fT0, const half_t* __restrict__ gT0,
               const half_t* __restrict__ h0, const float* __restrict__ L0,
               const float* __restrict__ src0, float* __restrict__ out0,
               const half_t* __restrict__ fT1, const half_t* __restrict__ gT1,
               const half_t* __restrict__ h1, const float* __restrict__ L1,
               const float* __restrict__ src1, float* __restrict__ out1,
               const float* __restrict__ gamma)
{
    __shared__ half_t h_lds[2][128][72];   // 36 KB
    __shared__ half_t PT[2][128][72];      // 36 KB

    const int m0 = blockIdx.x * 128;
    const int c0 = blockIdx.y * 128;
    const int b  = blockIdx.z & 3;
    const int sel = blockIdx.z >> 2;
    const half_t* fT = sel ? fT1 : fT0;
    const half_t* gT = sel ? gT1 : gT0;
    const half_t* h  = sel ? h1 : h0;
    const float*  Lg = sel ? L1 : L0;
    const float*  src = sel ? src1 : src0;
    float* out = sel ? out1 : out0;

    const int t = threadIdx.x;
    const int w = t >> 6, lane = t & 63;
    const int q = lane >> 4, mc = lane & 15;
    const int l5 = lane >> 5, l31 = lane & 31;

    const half_t* fTb = fT + (size_t)b * NN * 32;
    const half_t* gTb = gT + (size_t)b * NN * 32;
    const half_t* hb  = h + (size_t)b * CC * NN;
    const float*  Lb  = Lg + (size_t)b * NN;

    // persistent S B-frags: m = m0 + w*32 + u*16 + mc
    half8 gS[2];
    gS[0] = *(const half8*)&gTb[(size_t)(m0 + w * 32 + mc) * 32 + q * 8];
    gS[1] = *(const half8*)&gTb[(size_t)(m0 + w * 32 + 16 + mc) * 32 + q * 8];

    // h stage addressing: thread covers rows srow+32i, chunk sch
    const int srow = t >> 3;    // 0..31
    const int sch  = t & 7;     // 0..7

    // prefetch tile 0
    half8 hpre[4], fpre[4];
    #pragma unroll
    for (int i = 0; i < 4; ++i)
        hpre[i] = *(const half8*)&hb[(size_t)(c0 + srow + 32 * i) * NN + sch * 8];
    #pragma unroll
    for (int s = 0; s < 4; ++s)
        fpre[s] = *(const half8*)&fTb[(size_t)(s * 16 + mc) * 32 + q * 8];

    floatx16 acc[2][2];                  // [c-strip a][m-strip bm]
    #pragma unroll
    for (int a = 0; a < 2; ++a)
        #pragma unroll
        for (int bm = 0; bm < 2; ++bm)
            #pragma unroll
            for (int r = 0; r < 16; ++r) acc[a][bm][r] = 0.f;

    const int ca = (w >> 1) * 64;     // PV c-base for this wave
    const int mb = (w & 1) * 64;      // PV m-base (local)

    // PV consumer step on buffer pb
    auto pv_step = [&](int pb) {
        #pragma unroll
        for (int ch = 0; ch < 4; ++ch) {
            half8 B0 = *(const half8*)&PT[pb][mb + l31][ch * 16 + l5 * 8];
            half8 B1 = *(const half8*)&PT[pb][mb + 32 + l31][ch * 16 + l5 * 8];
            half8 A0 = *(const half8*)&h_lds[pb][ca + l31][ch * 16 + l5 * 8];
            half8 A1 = *(const half8*)&h_lds[pb][ca + 32 + l31][ch * 16 + l5 * 8];
            acc[0][0] = __builtin_amdgcn_mfma_f32_32x32x16_f16(A0, B0, acc[0][0], 0, 0, 0);
            acc[0][1] = __builtin_amdgcn_mfma_f32_32x32x16_f16(A0, B1, acc[0][1], 0, 0, 0);
            acc[1][0] = __builtin_amdgcn_mfma_f32_32x32x16_f16(A1, B0, acc[1][0], 0, 0, 0);
            acc[1][1] = __builtin_amdgcn_mfma_f32_32x32x16_f16(A1, B1, acc[1][1], 0, 0, 0);
        }
    };

    for (int it = 0; it < NN / 64; ++it) {
        const int nt = it * 64;
        const int cur = it & 1;
        __syncthreads();              // orders: prior reads of buf `cur` done;
                                      // writes of buf `cur^1` (iter it-1) visible
        // ---- stage h tile it into h_lds[cur]
        #pragma unroll
        for (int i = 0; i < 4; ++i)
            *(half8*)&h_lds[cur][srow + 32 * i][sch * 8] = hpre[i];

        // ---- S phase: tile it -> PT[cur] (this wave's 32-m strip)
        #pragma unroll
        for (int s = 0; s < 4; ++s) {
            float4 lv = *(const float4*)&Lb[nt + s * 16 + q * 4];
            #pragma unroll
            for (int u = 0; u < 2; ++u) {
                floatx4 S = __builtin_amdgcn_mfma_f32_16x16x32_f16(
                    fpre[s], gS[u], (floatx4){0.f, 0.f, 0.f, 0.f}, 0, 0, 0);
                half4 p;
                p[0] = (half_t)exp2f(fmaf(S[0], 1.44269504f, lv.x));
                p[1] = (half_t)exp2f(fmaf(S[1], 1.44269504f, lv.y));
                p[2] = (half_t)exp2f(fmaf(S[2], 1.44269504f, lv.z));
                p[3] = (half_t)exp2f(fmaf(S[3], 1.44269504f, lv.w));
                *(half4*)&PT[cur][w * 32 + u * 16 + mc][s * 16 + q * 4] = p;
            }
        }

        // ---- prefetch tile it+1 (no dependency on this tile's barriers)
        if (it < NN / 64 - 1) {
            const int ntn = nt + 64;
            #pragma unroll
            for (int i = 0; i < 4; ++i)
                hpre[i] = *(const half8*)&hb[(size_t)(c0 + srow + 32 * i) * NN + ntn + sch * 8];
            #pragma unroll
            for (int s = 0; s < 4; ++s)
                fpre[s] = *(const half8*)&fTb[(size_t)(ntn + s * 16 + mc) * 32 + q * 8];
        }

        // ---- PV on tile it-1 from buffer cur^1 (skip at it==0)
        if (it > 0) pv_step(cur ^ 1);
    }
    __syncthreads();                  // final tile's PT/h_lds writes visible
    pv_step((NN / 64 - 1) & 1);       // PV on last tile (buffer 1)

    // ---- epilogue: out = src + gamma * acc (D: col=l31, row=(r&3)+8*(r>>2)+4*l5)
    const float gm = gamma[0];
    const float* srcb = src + (size_t)b * CC * NN;
    float* outb = out + (size_t)b * CC * NN;
    #pragma unroll
    for (int a = 0; a < 2; ++a)
        #pragma unroll
        for (int bm = 0; bm < 2; ++bm) {
            const int m = m0 + mb + bm * 32 + l31;
            #pragma unroll
            for (int r = 0; r < 16; ++r) {
                int c = c0 + ca + a * 32 + (r & 3) + 8 * (r >> 2) + 4 * l5;
                size_t idx = (size_t)c * NN + m;
                outb[idx] = fmaf(gm, acc[a][bm][r], srcb[idx]);
            }
        }
}

// ---------------------------------------------------------------------------
extern "C" void kernel_launch(void* const* d_in, const int* in_sizes, int n_in,
                              void* d_out, int out_size, void* d_ws, size_t ws_size,
                              hipStream_t stream)
{
    const float* x   = (const float*)d_in[0];
    const float* y   = (const float*)d_in[1];
    const float* Wfx = (const float*)d_in[2];
    const float* bfx = (const float*)d_in[3];
    const float* Wgx = (const float*)d_in[4];
    const float* bgx = (const float*)d_in[5];
    const float* Whx = (const float*)d_in[6];
    const float* bhx = (const float*)d_in[7];
    const float* Wfy = (const float*)d_in[8];
    const float* bfy = (const float*)d_in[9];
    const float* Wgy = (const float*)d_in[10];
    const float* bgy = (const float*)d_in[11];
    const float* Why = (const float*)d_in[12];
    const float* bhy = (const float*)d_in[13];
    const float* gam = (const float*)d_in[14];

    const size_t SZ_XT = (size_t)BB * NN * CC;   // 4,194,304 halves
    const size_t SZ_FG = (size_t)BB * NN * 32;   // 524,288 halves
    half_t* xTx   = (half_t*)d_ws;
    half_t* xTy   = xTx + SZ_XT;
    half_t* hx    = xTy + SZ_XT;
    half_t* hy    = hx + SZ_XT;
    half_t* fxT   = hy + SZ_XT;
    half_t* gxT   = fxT + SZ_FG;
    half_t* fyT   = gxT + SZ_FG;
    half_t* gyT   = fyT + SZ_FG;
    half_t* Wfx_h = gyT + SZ_FG;
    half_t* Wgx_h = Wfx_h + 32 * CC;
    half_t* Wfy_h = Wgx_h + 32 * CC;
    half_t* Wgy_h = Wfy_h + 32 * CC;
    half_t* Whx_h = Wgy_h + 32 * CC;
    half_t* Why_h = Whx_h + CC * CC;
    float*  Lx    = (float*)(Why_h + CC * CC);
    float*  Ly    = Lx + (size_t)BB * NN;

    float* outx = (float*)d_out;
    float* outy = outx + (size_t)BB * CC * NN;

    cvt_w_kernel<<<dim3(64, 6), 256, 0, stream>>>(Wfx, Wgx, Whx, Wfy, Wgy, Why,
                                                  Wfx_h, Wgx_h, Whx_h, Wfy_h, Wgy_h, Why_h);

    transpose_cvt_kernel<<<dim3(64, 4, 8), 256, 0, stream>>>(x, y, xTx, xTy);

    proj_fg_kernel<<<dim3(64, 4, 2), 256, 0, stream>>>(
        xTx, xTy, Wfx_h, Wgx_h, Wfy_h, Wgy_h, bfx, bgx, bfy, bgy, fxT, gxT, fyT, gyT);

    proj_h_kernel<<<dim3(64, 2, 8), 256, 0, stream>>>(
        xTx, xTy, Whx_h, Why_h, bhx, bhy, hx, hy);

    // att_x rows: fy vs gx -> Lx ; att_y rows: fx vs gy -> Ly
    stats_kernel<<<dim3(128, 4, 2), 256, 0, stream>>>(fyT, gxT, fxT, gyT, Lx, Ly);

    pv_kernel<<<dim3(32, 2, 8), 256, 0, stream>>>(
        fyT, gxT, hx, Lx, x, outx,
        fxT, gyT, hy, Ly, y, outy, gam);
}